// Round 1
// baseline (195.104 us; speedup 1.0000x reference)
//
#include <hip/hip_runtime.h>

// AdjMlp: out[r, :] = sum over edges (r, c) of weight[c, :]
// v7 = v6 + scalar-predicated gather: counts/cols pulled to SGPRs via
// readfirstlane (wave-uniform), so per-slot weight loads are guarded by
// scalar branches (s_cmp/s_cbranch) instead of clamped-to-row-0 dummy loads.
// Removes ~110K dummy 1KB loads (deg-0/deg-1 rows) and moves the 8 load
// addresses to SGPR-base + lane*16 voffset form (VGPR pressure down).
// All-empty row-quad fast path streams zeros. 3 dispatches unchanged.

constexpr int OUT_F = 256;
constexpr int CAP = 8;          // bucket slots per row
constexpr int MAXOVF = 16384;   // overflow edge capacity

using f32x4 = __attribute__((ext_vector_type(4))) float;
using i32x4 = __attribute__((ext_vector_type(4))) int;

// ---------------- build ----------------

__global__ __launch_bounds__(256) void fill_k(const int* __restrict__ rows,
                                              const int* __restrict__ cols,
                                              int* __restrict__ counts,
                                              int* __restrict__ bucket,
                                              int* __restrict__ ovf_n,
                                              int* __restrict__ ovf,
                                              int nnz) {
    int e = blockIdx.x * 256 + threadIdx.x;
    if (e >= nnz) return;
    int r = rows[e];
    int c = cols[e];
    int slot = atomicAdd(&counts[r], 1);
    if (slot < CAP) {
        bucket[r * CAP + slot] = c;
    } else {
        int o = atomicAdd(ovf_n, 1);
        if (o < MAXOVF) { ovf[2 * o] = r; ovf[2 * o + 1] = c; }
    }
}

// ---------------- gather ----------------

// overflow resolution: scan the (tiny) ovf list for this row, accumulate in regs
__device__ __forceinline__ void ovf_scan(f32x4& acc, int row,
                                         const int* __restrict__ ovf_n,
                                         const int* __restrict__ ovf,
                                         const f32x4* __restrict__ w4, int lane) {
    int m = *ovf_n; if (m > MAXOVF) m = MAXOVF;
    for (int j = 0; j < m; j++) {
        if (ovf[2 * j] == row)
            acc += w4[(size_t)ovf[2 * j + 1] * 64 + lane];
    }
}

// slots 2..min(n,CAP)-1 + overflow; called only when n > 2 (wave-uniform, ~8%)
__device__ __forceinline__ void rare_tail(f32x4& acc, int n, const i32x4& b0,
                                          const i32x4* __restrict__ bucket4, int row,
                                          const f32x4* __restrict__ w4, int lane,
                                          const int* __restrict__ ovf_n,
                                          const int* __restrict__ ovf) {
    int m = n < CAP ? n : CAP;
    acc += w4[(size_t)__builtin_amdgcn_readfirstlane(b0.z) * 64 + lane];
    if (m > 3) acc += w4[(size_t)__builtin_amdgcn_readfirstlane(b0.w) * 64 + lane];
    if (m > 4) {
        i32x4 b1 = __builtin_nontemporal_load(bucket4 + (size_t)row * 2 + 1);
        acc += w4[(size_t)__builtin_amdgcn_readfirstlane(b1.x) * 64 + lane];
        if (m > 5) acc += w4[(size_t)__builtin_amdgcn_readfirstlane(b1.y) * 64 + lane];
        if (m > 6) acc += w4[(size_t)__builtin_amdgcn_readfirstlane(b1.z) * 64 + lane];
        if (m > 7) acc += w4[(size_t)__builtin_amdgcn_readfirstlane(b1.w) * 64 + lane];
        if (n > CAP) ovf_scan(acc, row, ovf_n, ovf, w4, lane);
    }
}

__global__ __launch_bounds__(256) void gather_k(const int* __restrict__ counts,
                                                const i32x4* __restrict__ bucket4,
                                                const f32x4* __restrict__ w4,
                                                f32x4* __restrict__ out4,
                                                const int* __restrict__ ovf_n,
                                                const int* __restrict__ ovf,
                                                int nrows) {
    const int lane = threadIdx.x & 63;
    int wid = (blockIdx.x << 2) + (threadIdx.x >> 6);
    wid = __builtin_amdgcn_readfirstlane(wid);   // wave-uniform -> scalar regs
    const int row0 = wid << 2;                   // 4 rows per wave
    if (row0 >= nrows) return;

    const f32x4 z = {0.f, 0.f, 0.f, 0.f};

    if (row0 + 4 <= nrows) {
        // single-use metadata: nontemporal (don't pollute L2; keep it for weight)
        const i32x4 cntv = __builtin_nontemporal_load((const i32x4*)(counts + row0));
        // counts are wave-uniform -> SGPRs, so all guards below are scalar branches
        const int n0 = __builtin_amdgcn_readfirstlane(cntv.x);
        const int n1 = __builtin_amdgcn_readfirstlane(cntv.y);
        const int n2 = __builtin_amdgcn_readfirstlane(cntv.z);
        const int n3 = __builtin_amdgcn_readfirstlane(cntv.w);

        f32x4* o = out4 + (size_t)row0 * 64 + lane;
        if ((n0 | n1 | n2 | n3) == 0) {
            // ~1.8% of waves: all four rows empty -> stream 4KB of zeros
            __builtin_nontemporal_store(z, o);
            __builtin_nontemporal_store(z, o + 64);
            __builtin_nontemporal_store(z, o + 128);
            __builtin_nontemporal_store(z, o + 192);
            return;
        }

        // bucket loads only for non-empty rows (scalar-predicated)
        i32x4 ba, bb, bc, bd;
        if (n0 > 0) ba = __builtin_nontemporal_load(bucket4 + (size_t)(row0 + 0) * 2);
        if (n1 > 0) bb = __builtin_nontemporal_load(bucket4 + (size_t)(row0 + 1) * 2);
        if (n2 > 0) bc = __builtin_nontemporal_load(bucket4 + (size_t)(row0 + 2) * 2);
        if (n3 > 0) bd = __builtin_nontemporal_load(bucket4 + (size_t)(row0 + 3) * 2);

        // issue all valid weight-row loads first (keeps up to 8 x 1KB in flight),
        // addresses are SGPR-base + lane*16 (cols readfirstlane'd to scalar)
        f32x4 va0, va1, vb0, vb1, vc0, vc1, vd0, vd1;
        if (n0 > 0) va0 = w4[(size_t)__builtin_amdgcn_readfirstlane(ba.x) * 64 + lane];
        if (n0 > 1) va1 = w4[(size_t)__builtin_amdgcn_readfirstlane(ba.y) * 64 + lane];
        if (n1 > 0) vb0 = w4[(size_t)__builtin_amdgcn_readfirstlane(bb.x) * 64 + lane];
        if (n1 > 1) vb1 = w4[(size_t)__builtin_amdgcn_readfirstlane(bb.y) * 64 + lane];
        if (n2 > 0) vc0 = w4[(size_t)__builtin_amdgcn_readfirstlane(bc.x) * 64 + lane];
        if (n2 > 1) vc1 = w4[(size_t)__builtin_amdgcn_readfirstlane(bc.y) * 64 + lane];
        if (n3 > 0) vd0 = w4[(size_t)__builtin_amdgcn_readfirstlane(bd.x) * 64 + lane];
        if (n3 > 1) vd1 = w4[(size_t)__builtin_amdgcn_readfirstlane(bd.y) * 64 + lane];

        // accumulate (each v* only touched under the same scalar condition that
        // loaded it, so no dummy loads and no undef reads)
        f32x4 a0 = z, a1 = z, a2 = z, a3 = z;
        if (n0 > 0) {
            a0 = va0;
            if (n0 > 1) a0 += va1;
            if (n0 > 2) rare_tail(a0, n0, ba, bucket4, row0 + 0, w4, lane, ovf_n, ovf);
        }
        if (n1 > 0) {
            a1 = vb0;
            if (n1 > 1) a1 += vb1;
            if (n1 > 2) rare_tail(a1, n1, bb, bucket4, row0 + 1, w4, lane, ovf_n, ovf);
        }
        if (n2 > 0) {
            a2 = vc0;
            if (n2 > 1) a2 += vc1;
            if (n2 > 2) rare_tail(a2, n2, bc, bucket4, row0 + 2, w4, lane, ovf_n, ovf);
        }
        if (n3 > 0) {
            a3 = vd0;
            if (n3 > 1) a3 += vd1;
            if (n3 > 2) rare_tail(a3, n3, bd, bucket4, row0 + 3, w4, lane, ovf_n, ovf);
        }

        // 4KB contiguous nontemporal store per wave (write-once stream)
        __builtin_nontemporal_store(a0, o);
        __builtin_nontemporal_store(a1, o + 64);
        __builtin_nontemporal_store(a2, o + 128);
        __builtin_nontemporal_store(a3, o + 192);
    } else {
        for (int r = row0; r < nrows; r++) {
            const int n = counts[r];
            f32x4 acc = z;
            if (n > 0) {
                const i32x4 b0 = bucket4[(size_t)r * 2];
                acc += w4[(size_t)__builtin_amdgcn_readfirstlane(b0.x) * 64 + lane];
                if (n > 1) acc += w4[(size_t)__builtin_amdgcn_readfirstlane(b0.y) * 64 + lane];
                if (n > 2) rare_tail(acc, n, b0, bucket4, r, w4, lane, ovf_n, ovf);
            }
            __builtin_nontemporal_store(acc, out4 + (size_t)r * 64 + lane);
        }
    }
}

// ---------------- emergency fallback (no workspace): atomic scatter ----------

__global__ __launch_bounds__(256) void zero_f4(float4* __restrict__ out, int n4) {
    int i = blockIdx.x * 256 + threadIdx.x;
    if (i < n4) out[i] = make_float4(0.f, 0.f, 0.f, 0.f);
}

__global__ __launch_bounds__(256) void scatter_kernel(const int* __restrict__ rows,
                                                      const int* __restrict__ cols,
                                                      const float* __restrict__ weight,
                                                      float* __restrict__ out, int nnz) {
    const int lane = threadIdx.x & 63;
    const int edge = blockIdx.x * 4 + (threadIdx.x >> 6);
    if (edge >= nnz) return;
    const int r = rows[edge];
    const int c = cols[edge];
    const float4 v = ((const float4*)(weight + (size_t)c * OUT_F))[lane];
    float* o = out + (size_t)r * OUT_F + (size_t)lane * 4;
    atomicAdd(o + 0, v.x);
    atomicAdd(o + 1, v.y);
    atomicAdd(o + 2, v.z);
    atomicAdd(o + 3, v.w);
}

// ---------------- launch ----------------

extern "C" void kernel_launch(void* const* d_in, const int* in_sizes, int n_in,
                              void* d_out, int out_size, void* d_ws, size_t ws_size,
                              hipStream_t stream) {
    const int* adj = (const int*)d_in[0];          // [2, nnz] int32
    const int nnz = in_sizes[0] / 2;
    const int* rows = adj;
    const int* cols = adj + nnz;
    const float* weight = (const float*)d_in[2];   // [IN_F, 256] fp32
    float* out = (float*)d_out;                    // [nrows, 256] fp32
    const int nrows = out_size / OUT_F;

    // workspace (ints): counts[nrows] | ovf_n[4] | ovf[2*MAXOVF] | bucket[nrows*CAP]
    // only counts+ovf_n need zeroing (400KB + 16B)
    const size_t ovfnOff   = (size_t)nrows;                  // 16B-aligned (nrows%4==0)
    const size_t ovfOff    = ovfnOff + 4;
    const size_t bucketOff = ovfOff + 2 * MAXOVF;            // stays 16B-aligned
    const size_t need      = (bucketOff + (size_t)nrows * CAP) * 4;

    if (ws_size >= need && (nrows & 3) == 0) {
        int* wsI    = (int*)d_ws;
        int* counts = wsI;
        int* ovf_n  = wsI + ovfnOff;
        int* ovf    = wsI + ovfOff;
        int* bucket = wsI + bucketOff;

        hipMemsetAsync(counts, 0, ovfOff * 4, stream);       // counts + ovf_n only
        fill_k<<<(nnz + 255) / 256, 256, 0, stream>>>(rows, cols, counts, bucket,
                                                      ovf_n, ovf, nnz);
        gather_k<<<(nrows + 15) / 16, 256, 0, stream>>>(counts, (const i32x4*)bucket,
                                                        (const f32x4*)weight,
                                                        (f32x4*)out, ovf_n, ovf, nrows);
    } else {
        // no usable workspace / odd shape: zero + atomic scatter (correct, slower)
        const int n4 = out_size / 4;
        zero_f4<<<(n4 + 255) / 256, 256, 0, stream>>>((float4*)out, n4);
        scatter_kernel<<<(nnz + 3) / 4, 256, 0, stream>>>(rows, cols, weight, out, nnz);
    }
}